// Round 3
// baseline (921.370 us; speedup 1.0000x reference)
//
#include <hip/hip_runtime.h>
#include <cstdint>
#include <cstddef>

#define B_ 16
#define C_ 256
#define T_ 128
#define V_ 64
#define K_ 8
#define O_ 256
#define TN 8192      /* T_*V_ */
#define NBT 131072   /* B_*T_*V_ : BN sample count */

typedef unsigned short ushort_t;
typedef __attribute__((ext_vector_type(8))) short short8;
typedef __attribute__((ext_vector_type(4))) float f32x4;

/* ---- workspace layout (float offsets) ---- */
#define OFF_TP     0          /* [B][C][V] 262144; reused for w-images (bf16) after x1x2 */
#define OFF_X1     262144
#define OFF_X2     524288
#define OFF_STATS  786432     /* ssum,ssq,hsum,hsq 4*256 */
#define OFF_SSC    787456
#define OFF_HSC    787968
#define OFF_ADA    788480     /* [B][K][V][V] 524288 */
#define OFF_Z      1312768    /* z fp32 [B][O][TN] 33554432 */
#define OFF_H2     34867200   /* h2 bf16 image (16.7M ushort) in old h2 region */

__device__ inline ushort_t f2bf(float f) {
    unsigned u = __builtin_bit_cast(unsigned, f);
    unsigned r = (u + 0x7FFFu + ((u >> 16) & 1u)) >> 16;
    return (ushort_t)r;
}
__device__ inline unsigned pack2(float a, float b) {
    return (unsigned)f2bf(a) | ((unsigned)f2bf(b) << 16);
}
__device__ inline void gload_lds16(const void* g, void* l) {
    __builtin_amdgcn_global_load_lds((const __attribute__((address_space(1))) unsigned int*)g,
                                     (__attribute__((address_space(3))) unsigned int*)l, 16, 0, 0);
}

/* x [b][c][t][v] fp32 -> bf16 frag image ((b*128+t)*8+cc)*2048 + q*512 + v*8 + cl
   (c = cc*32+q*8+cl); fused: per-(b,c,v) mean over t via atomic partials into tp */
__global__ __launch_bounds__(256) void k_xpose2(const float* __restrict__ x,
                                                ushort_t* __restrict__ img,
                                                float* __restrict__ tp) {
    __shared__ float Lt[64][65];
    int tb = blockIdx.x;         /* 8 blocks of 16 t */
    int cg = blockIdx.y;         /* 4 groups of 64 c */
    int b  = blockIdx.z;
    int tid = threadIdx.x;
    int c0 = cg * 64;
    float4 macc[4] = {};
    for (int tt = 0; tt < 16; tt++) {
        int t = tb * 16 + tt;
        #pragma unroll
        for (int i = 0; i < 4; i++) {
            int e = tid + i * 256;
            int ci = e >> 4, v4 = e & 15;
            float4 v = *(const float4*)(x + ((size_t)(b * C_ + c0 + ci) * 128 + t) * 64 + v4 * 4);
            *(float4*)&Lt[ci][v4 * 4] = v;
            macc[i].x += v.x; macc[i].y += v.y; macc[i].z += v.z; macc[i].w += v.w;
        }
        __syncthreads();
        #pragma unroll
        for (int i = 0; i < 2; i++) {
            int p = tid + i * 256;
            int v = p & 63, qq = (p >> 6) & 3, cc2 = p >> 8;
            int cl0 = cc2 * 32 + qq * 8;
            uint4 u;
            u.x = pack2(Lt[cl0 + 0][v], Lt[cl0 + 1][v]);
            u.y = pack2(Lt[cl0 + 2][v], Lt[cl0 + 3][v]);
            u.z = pack2(Lt[cl0 + 4][v], Lt[cl0 + 5][v]);
            u.w = pack2(Lt[cl0 + 6][v], Lt[cl0 + 7][v]);
            int cc = cg * 2 + cc2;
            size_t dst = ((size_t)(b * 128 + t) * 8 + cc) * 2048 + qq * 512 + v * 8;
            *(uint4*)(img + dst) = u;
        }
        __syncthreads();
    }
    const float r = 1.0f / (float)T_;
    #pragma unroll
    for (int i = 0; i < 4; i++) {
        int e = tid + i * 256;
        int ci = e >> 4, v4 = e & 15;
        float* dst = tp + (size_t)(b * C_ + c0 + ci) * V_ + v4 * 4;
        atomicAdd(&dst[0], macc[i].x * r); atomicAdd(&dst[1], macc[i].y * r);
        atomicAdd(&dst[2], macc[i].z * r); atomicAdd(&dst[3], macc[i].w * r);
    }
}

/* x1/x2 partials over 64-c chunk, atomic into zeroed x1/x2 */
__global__ __launch_bounds__(256) void k_x1x2a(const float* __restrict__ tp,
                                               const float* __restrict__ w1, const float* __restrict__ b1,
                                               const float* __restrict__ w2, const float* __restrict__ b2,
                                               float* __restrict__ x1, float* __restrict__ x2) {
    int og = blockIdx.x, cc = blockIdx.y, b = blockIdx.z;
    int o  = og * 16 + (threadIdx.x >> 4);
    int v4 = threadIdx.x & 15;
    const float4* ptp = (const float4*)(tp + (size_t)b * C_ * V_) + v4;
    float4 s1 = {0.f,0.f,0.f,0.f}, s2 = {0.f,0.f,0.f,0.f};
    int c0 = cc * 64;
    for (int c = c0; c < c0 + 64; c++) {
        float4 tv = ptp[c * 16];
        float wa = w1[o * C_ + c];
        float wb = w2[o * C_ + c];
        s1.x += tv.x * wa; s1.y += tv.y * wa; s1.z += tv.z * wa; s1.w += tv.w * wa;
        s2.x += tv.x * wb; s2.y += tv.y * wb; s2.z += tv.z * wb; s2.w += tv.w * wb;
    }
    if (cc == 0) {
        float bv1 = b1[o], bv2 = b2[o];
        s1.x += bv1; s1.y += bv1; s1.z += bv1; s1.w += bv1;
        s2.x += bv2; s2.y += bv2; s2.z += bv2; s2.w += bv2;
    }
    float* p1 = x1 + (size_t)(b * O_ + o) * V_ + v4 * 4;
    float* p2 = x2 + (size_t)(b * O_ + o) * V_ + v4 * 4;
    atomicAdd(&p1[0], s1.x); atomicAdd(&p1[1], s1.y); atomicAdd(&p1[2], s1.z); atomicAdd(&p1[3], s1.w);
    atomicAdd(&p2[0], s2.x); atomicAdd(&p2[1], s2.y); atomicAdd(&p2[2], s2.z); atomicAdd(&p2[3], s2.w);
}

/* ada[b,k,v,w] = softmax_v( sum_c x1[b,k,c,v]*x2[b,k,c,w] ) one wave per (b,k,w) */
__global__ __launch_bounds__(64) void k_ada(const float* __restrict__ x1,
                                            const float* __restrict__ x2,
                                            float* __restrict__ ada) {
    int bid = blockIdx.x;
    int w = bid & 63;
    int k = (bid >> 6) & 7;
    int b = bid >> 9;
    int v = threadIdx.x;
    const float* p1 = x1 + ((size_t)b * O_ + k * 32) * V_;
    const float* p2 = x2 + ((size_t)b * O_ + k * 32) * V_;
    float s = 0.f;
    #pragma unroll
    for (int c = 0; c < 32; c++) s += p1[c * V_ + v] * p2[c * V_ + w];
    float m = s;
    #pragma unroll
    for (int off = 32; off >= 1; off >>= 1) m = fmaxf(m, __shfl_xor(m, off, 64));
    float e = __expf(s - m);
    float sum = e;
    #pragma unroll
    for (int off = 32; off >= 1; off >>= 1) sum += __shfl_xor(sum, off, 64);
    ada[((size_t)(b * K_ + k) * V_ + v) * V_ + w] = e / sum;
}

/* w[256][256] fp32 -> bf16 image: [cc 8][q 4][ol 256][cl 8] */
__global__ __launch_bounds__(256) void k_wconv(const float* __restrict__ w,
                                               ushort_t* __restrict__ img) {
    int flat = blockIdx.x * 256 + threadIdx.x;
    #pragma unroll
    for (int g2 = 0; g2 < 2; g2++) {
        int gi = flat * 2 + g2;
        int cc = gi >> 10;
        int q  = (gi >> 8) & 3;
        int ol = gi & 255;
        int c0 = cc * 32 + q * 8;
        const float* src = w + (size_t)ol * C_ + c0;
        float4 f0 = *(const float4*)src;
        float4 f1 = *(const float4*)(src + 4);
        uint4 u;
        u.x = pack2(f0.x, f0.y); u.y = pack2(f0.z, f0.w);
        u.z = pack2(f1.x, f1.y); u.w = pack2(f1.z, f1.w);
        *(uint4*)(img + (size_t)gi * 8) = u;
    }
}

/* out[b][o][n] = sum_c W[o][c] X[b][n][c] + bias[o], fp32 out + fused BN stats. */
__global__ __launch_bounds__(256) void k_gemm(const ushort_t* __restrict__ ximg,
                                              const ushort_t* __restrict__ wimg,
                                              const float* __restrict__ bias,
                                              float* __restrict__ out,
                                              float* __restrict__ psum,
                                              float* __restrict__ psumsq) {
    __shared__ __align__(16) ushort_t sh[2048];
    int tid = threadIdx.x;
    int nblk = blockIdx.x, b = blockIdx.z;
    int wm = tid >> 6;
    int lane = tid & 63, ln = lane & 15, q = lane >> 4;
    f32x4 acc[4][4];
    #pragma unroll
    for (int mt = 0; mt < 4; mt++)
        #pragma unroll
        for (int nt = 0; nt < 4; nt++) acc[mt][nt] = (f32x4){0.f, 0.f, 0.f, 0.f};
    const ushort_t* xbase = ximg + ((size_t)(b * 128 + nblk) * 8) * 2048;
    for (int cc = 0; cc < 8; cc++) {
        gload_lds16(xbase + (size_t)cc * 2048 + wm * 512 + lane * 8, &sh[wm * 512]);
        __syncthreads();
        short8 a[4], bb[4];
        const ushort_t* wc = wimg + (size_t)cc * 8192 + q * 2048;
        #pragma unroll
        for (int mt = 0; mt < 4; mt++)
            a[mt] = *(const short8*)(wc + (wm * 64 + mt * 16 + ln) * 8);
        #pragma unroll
        for (int nt = 0; nt < 4; nt++)
            bb[nt] = *(const short8*)&sh[q * 512 + (nt * 16 + ln) * 8];
        #pragma unroll
        for (int mt = 0; mt < 4; mt++)
            #pragma unroll
            for (int nt = 0; nt < 4; nt++)
                acc[mt][nt] = __builtin_amdgcn_mfma_f32_16x16x32_bf16(a[mt], bb[nt], acc[mt][nt], 0, 0, 0);
        __syncthreads();
    }
    int n_base = nblk * 64;
    #pragma unroll
    for (int mt = 0; mt < 4; mt++) {
        int o0 = wm * 64 + mt * 16 + q * 4;
        #pragma unroll
        for (int r = 0; r < 4; r++) {
            float bv = bias[o0 + r];
            float v0 = acc[mt][0][r] + bv, v1 = acc[mt][1][r] + bv;
            float v2 = acc[mt][2][r] + bv, v3 = acc[mt][3][r] + bv;
            float* orow = out + ((size_t)(b * O_ + o0 + r)) * TN + n_base + ln;
            orow[0] = v0; orow[16] = v1; orow[32] = v2; orow[48] = v3;
            float s  = v0 + v1 + v2 + v3;
            float sq = v0 * v0 + v1 * v1 + v2 * v2 + v3 * v3;
            #pragma unroll
            for (int off = 1; off <= 8; off <<= 1) {
                s  += __shfl_xor(s,  off, 64);
                sq += __shfl_xor(sq, off, 64);
            }
            if (ln == 0) {
                atomicAdd(&psum[o0 + r],   s);
                atomicAdd(&psumsq[o0 + r], sq);
            }
        }
    }
}

__global__ void k_finalize(const float* __restrict__ psum, const float* __restrict__ psumsq,
                           const float* __restrict__ gamma, const float* __restrict__ betap,
                           float* __restrict__ scale, float* __restrict__ shift) {
    int o = threadIdx.x;
    float mean = psum[o]   * (1.0f / (float)NBT);
    float var  = psumsq[o] * (1.0f / (float)NBT) - mean * mean;
    float sc = gamma[o] * rsqrtf(var + 1e-5f);
    scale[o] = sc;
    shift[o] = betap[o] - mean * sc;
}

/* MFMA einsum: per block (b,k,q,mh): 8 channels o1=k*32+q*8+cl, t-range mh*64..+63.
   h2img[(b*128+t)*8+k, q*512 + w*8 + cl] = sum_v relu(bn(z[b,o1,t,v])) * A[b,k,c,v,w] */
__global__ __launch_bounds__(256) void k_einsum_mfma(const float* __restrict__ z,
                                                     const float* __restrict__ x1,
                                                     const float* __restrict__ x2,
                                                     const float* __restrict__ ada,
                                                     const float* __restrict__ A_param,
                                                     const float* __restrict__ alphap,
                                                     const float* __restrict__ betap,
                                                     const float* __restrict__ scale,
                                                     const float* __restrict__ shift,
                                                     ushort_t* __restrict__ h2img) {
    __shared__ float Coms[4096];                 /* A_param[k] + beta*ada[b,k] */
    __shared__ float x1s[8][64], x2s[8][64];
    __shared__ __align__(16) ushort_t stg[8192]; /* [t_local 16][w 64][cl 8] */
    int tid = threadIdx.x;
    int bid = blockIdx.x;
    int mh = bid & 1;
    int q  = (bid >> 1) & 3;
    int k  = (bid >> 3) & 7;
    int b  = bid >> 6;
    int wm = tid >> 6;
    int lane = tid & 63, ln = lane & 15, qq = lane >> 4;
    float alpha = alphap[0], beta = betap[0];

    const float* Apk = A_param + (size_t)k * 4096;
    const float* adk = ada + (size_t)(b * K_ + k) * 4096;
    #pragma unroll
    for (int i = 0; i < 4; i++) {
        int e4 = tid + i * 256;
        float4 ap = *(const float4*)(Apk + (size_t)e4 * 4);
        float4 ad = *(const float4*)(adk + (size_t)e4 * 4);
        float4 cm = {ap.x + beta * ad.x, ap.y + beta * ad.y,
                     ap.z + beta * ad.z, ap.w + beta * ad.w};
        *(float4*)&Coms[e4 * 4] = cm;
    }
    #pragma unroll
    for (int i = 0; i < 2; i++) {
        int e = tid + i * 256;
        int cl = e >> 6, v = e & 63;
        int o1 = k * 32 + q * 8 + cl;
        x1s[cl][v] = x1[((size_t)b * O_ + o1) * V_ + v];
        x2s[cl][v] = x2[((size_t)b * O_ + o1) * V_ + v];
    }
    __syncthreads();

    /* B-operand frags for this wave's 2 channels, built in-register */
    short8 bfrag[2][2][4];
    #pragma unroll
    for (int half = 0; half < 2; half++) {
        int cl = wm + half * 4;
        #pragma unroll
        for (int kk = 0; kk < 2; kk++) {
            float x1v[8];
            #pragma unroll
            for (int j = 0; j < 8; j++) x1v[j] = x1s[cl][kk * 32 + qq * 8 + j];
            #pragma unroll
            for (int nt = 0; nt < 4; nt++) {
                int w = nt * 16 + ln;
                float x2v = x2s[cl][w];
                float av[8];
                #pragma unroll
                for (int j = 0; j < 8; j++) {
                    int v = kk * 32 + qq * 8 + j;
                    float d = x1v[j] - x2v;
                    float ax = fabsf(d);
                    float e2 = __expf(-2.f * ax);
                    float th = copysignf((1.f - e2) / (1.f + e2), d);
                    av[j] = Coms[v * 64 + w] + alpha * th;
                }
                uint4 bp;
                bp.x = pack2(av[0], av[1]); bp.y = pack2(av[2], av[3]);
                bp.z = pack2(av[4], av[5]); bp.w = pack2(av[6], av[7]);
                bfrag[half][kk][nt] = __builtin_bit_cast(short8, bp);
            }
        }
    }

    int o1a = k * 32 + q * 8 + wm;
    int o1b = o1a + 4;
    float scv[2] = {scale[o1a], scale[o1b]};
    float shv[2] = {shift[o1a], shift[o1b]};
    const float* zr[2] = {z + ((size_t)b * O_ + o1a) * TN, z + ((size_t)b * O_ + o1b) * TN};
    size_t obase = ((size_t)(b * 128) * 8 + k) * 2048 + q * 512;

    for (int mt = mh * 4; mt < mh * 4 + 4; mt++) {
        f32x4 acc[2][4];
        #pragma unroll
        for (int half = 0; half < 2; half++)
            #pragma unroll
            for (int nt = 0; nt < 4; nt++) acc[half][nt] = (f32x4){0.f, 0.f, 0.f, 0.f};
        #pragma unroll
        for (int half = 0; half < 2; half++) {
            float s = scv[half], h = shv[half];
            #pragma unroll
            for (int kk = 0; kk < 2; kk++) {
                const float* src = zr[half] + (mt * 16 + ln) * 64 + kk * 32 + qq * 8;
                float4 a0 = *(const float4*)src;
                float4 a1 = *(const float4*)(src + 4);
                uint4 hp;
                hp.x = pack2(fmaxf(a0.x * s + h, 0.f), fmaxf(a0.y * s + h, 0.f));
                hp.y = pack2(fmaxf(a0.z * s + h, 0.f), fmaxf(a0.w * s + h, 0.f));
                hp.z = pack2(fmaxf(a1.x * s + h, 0.f), fmaxf(a1.y * s + h, 0.f));
                hp.w = pack2(fmaxf(a1.z * s + h, 0.f), fmaxf(a1.w * s + h, 0.f));
                short8 hf = __builtin_bit_cast(short8, hp);
                #pragma unroll
                for (int nt = 0; nt < 4; nt++)
                    acc[half][nt] = __builtin_amdgcn_mfma_f32_16x16x32_bf16(hf, bfrag[half][kk][nt], acc[half][nt], 0, 0, 0);
            }
        }
        #pragma unroll
        for (int half = 0; half < 2; half++) {
            int cl = wm + half * 4;
            #pragma unroll
            for (int nt = 0; nt < 4; nt++)
                #pragma unroll
                for (int r = 0; r < 4; r++)
                    stg[(qq * 4 + r) * 512 + (nt * 16 + ln) * 8 + cl] = f2bf(acc[half][nt][r]);
        }
        __syncthreads();
        #pragma unroll
        for (int ii = 0; ii < 4; ii++) {
            int u = tid + ii * 256;
            int tl = u >> 6, off = u & 63;
            ((uint4*)(h2img + obase + (size_t)(mt * 16 + tl) * 16384))[off] = ((const uint4*)stg)[u];
        }
        __syncthreads();
    }
}

/* out = relu(bn(u) + x), in-place on d_out */
__global__ __launch_bounds__(256) void k_final(float* __restrict__ out,
                                               const float* __restrict__ x,
                                               const float* __restrict__ scale,
                                               const float* __restrict__ shift) {
    size_t i4 = (size_t)blockIdx.x * 256 + threadIdx.x;
    int o = (int)((i4 >> 11) & 255);
    float4 u  = ((const float4*)out)[i4];
    float4 xv = ((const float4*)x)[i4];
    float sc = scale[o], sh = shift[o];
    u.x = fmaxf(u.x * sc + sh + xv.x, 0.f);
    u.y = fmaxf(u.y * sc + sh + xv.y, 0.f);
    u.z = fmaxf(u.z * sc + sh + xv.z, 0.f);
    u.w = fmaxf(u.w * sc + sh + xv.w, 0.f);
    ((float4*)out)[i4] = u;
}

extern "C" void kernel_launch(void* const* d_in, const int* in_sizes, int n_in,
                              void* d_out, int out_size, void* d_ws, size_t ws_size,
                              hipStream_t stream) {
    const float* x          = (const float*)d_in[0];
    const float* A_param    = (const float*)d_in[1];
    const float* alphap     = (const float*)d_in[2];
    const float* betap      = (const float*)d_in[3];
    const float* w1         = (const float*)d_in[4];
    const float* b1         = (const float*)d_in[5];
    const float* w2         = (const float*)d_in[6];
    const float* b2         = (const float*)d_in[7];
    const float* stem_w     = (const float*)d_in[8];
    const float* stem_b     = (const float*)d_in[9];
    const float* stem_gamma = (const float*)d_in[10];
    const float* stem_beta  = (const float*)d_in[11];
    const float* head_w     = (const float*)d_in[12];
    const float* head_b     = (const float*)d_in[13];
    const float* head_gamma = (const float*)d_in[14];
    const float* head_beta  = (const float*)d_in[15];

    float* W      = (float*)d_ws;
    float* tp     = W + OFF_TP;
    float* x1b    = W + OFF_X1;
    float* x2b    = W + OFF_X2;
    float* ssum   = W + OFF_STATS;
    float* ssq    = W + OFF_STATS + 256;
    float* hsum   = W + OFF_STATS + 512;
    float* hsq    = W + OFF_STATS + 768;
    float* sscale = W + OFF_SSC;
    float* sshift = W + OFF_SSC + 256;
    float* hscale = W + OFF_HSC;
    float* hshift = W + OFF_HSC + 256;
    float* adab   = W + OFF_ADA;
    float* zbuf   = W + OFF_Z;
    float* uout   = (float*)d_out;

    ushort_t* xTimg  = (ushort_t*)d_out;               /* dead before head GEMM writes */
    ushort_t* wsimg  = (ushort_t*)(W + OFF_TP);        /* tp region, after x1x2 */
    ushort_t* whimg  = (ushort_t*)(W + OFF_TP + 32768);
    ushort_t* h2img  = (ushort_t*)(W + OFF_H2);

    /* zero tp, x1, x2, stats (atomic accumulation targets) */
    hipMemsetAsync(W, 0, (size_t)(OFF_STATS + 1024) * sizeof(float), stream);

    k_xpose2<<<dim3(8, 4, 16), 256, 0, stream>>>(x, xTimg, tp);
    k_x1x2a<<<dim3(16, 4, 16), 256, 0, stream>>>(tp, w1, b1, w2, b2, x1b, x2b);
    k_ada<<<8192, 64, 0, stream>>>(x1b, x2b, adab);
    k_wconv<<<16, 256, 0, stream>>>(stem_w, wsimg);
    k_wconv<<<16, 256, 0, stream>>>(head_w, whimg);

    k_gemm<<<dim3(128, 1, 16), 256, 0, stream>>>(xTimg, wsimg, stem_b, zbuf, ssum, ssq);
    k_finalize<<<1, 256, 0, stream>>>(ssum, ssq, stem_gamma, stem_beta, sscale, sshift);

    k_einsum_mfma<<<1024, 256, 0, stream>>>(zbuf, x1b, x2b, adab, A_param, alphap, betap,
                                            sscale, sshift, h2img);

    k_gemm<<<dim3(128, 1, 16), 256, 0, stream>>>(h2img, whimg, head_b, uout, hsum, hsq);
    k_finalize<<<1, 256, 0, stream>>>(hsum, hsq, head_gamma, head_beta, hscale, hshift);
    k_final<<<32768, 256, 0, stream>>>(uout, x, hscale, hshift);
}

// Round 4
// 531.213 us; speedup vs baseline: 1.7345x; 1.7345x over previous
//
#include <hip/hip_runtime.h>
#include <cstdint>
#include <cstddef>

#define B_ 16
#define C_ 256
#define T_ 128
#define V_ 64
#define K_ 8
#define O_ 256
#define TN 8192      /* T_*V_ */
#define NBT 131072   /* B_*T_*V_ : BN sample count */
#define NSL 32       /* stats slices (atomic contention spreader) */

typedef unsigned short ushort_t;
typedef __attribute__((ext_vector_type(8))) short short8;
typedef __attribute__((ext_vector_type(4))) float f32x4;

/* ---- workspace layout (float offsets) ---- */
#define OFF_TP     0          /* [B][C][V] 262144; reused for w-images (bf16) after x1x2 */
#define OFF_X1     262144
#define OFF_X2     524288
#define OFF_STATS  786432     /* 4 arrays x [NSL][256] = 32768 */
#define OFF_SSC    819200     /* stem scale/shift 512 */
#define OFF_HSC    819712
#define OFF_ADA    820224     /* [B][K][V][V] 524288 -> ends 1344512 */
#define OFF_Z      1344512    /* z bf16 [B][O][TN] : 33554432 ushort = 16777216 f32; u reuses it */
#define OFF_H2     34867200   /* h2 bf16 image 16777216 ushort */

__device__ inline ushort_t f2bf(float f) {
    unsigned u = __builtin_bit_cast(unsigned, f);
    unsigned r = (u + 0x7FFFu + ((u >> 16) & 1u)) >> 16;
    return (ushort_t)r;
}
__device__ inline unsigned pack2(float a, float b) {
    return (unsigned)f2bf(a) | ((unsigned)f2bf(b) << 16);
}
__device__ inline float bf2f_lo(unsigned u) { return __builtin_bit_cast(float, u << 16); }
__device__ inline float bf2f_hi(unsigned u) { return __builtin_bit_cast(float, u & 0xFFFF0000u); }
__device__ inline void gload_lds16(const void* g, void* l) {
    __builtin_amdgcn_global_load_lds((const __attribute__((address_space(1))) unsigned int*)g,
                                     (__attribute__((address_space(3))) unsigned int*)l, 16, 0, 0);
}

/* x [b][c][t][v] fp32 -> bf16 frag image ((b*128+t)*8+cc)*2048 + q*512 + v*8 + cl
   (c = cc*32+q*8+cl); fused: per-(b,c,v) mean over t via atomic partials into tp */
__global__ __launch_bounds__(256) void k_xpose2(const float* __restrict__ x,
                                                ushort_t* __restrict__ img,
                                                float* __restrict__ tp) {
    __shared__ float Lt[64][65];
    int tb = blockIdx.x;
    int cg = blockIdx.y;
    int b  = blockIdx.z;
    int tid = threadIdx.x;
    int c0 = cg * 64;
    float4 macc[4] = {};
    for (int tt = 0; tt < 16; tt++) {
        int t = tb * 16 + tt;
        #pragma unroll
        for (int i = 0; i < 4; i++) {
            int e = tid + i * 256;
            int ci = e >> 4, v4 = e & 15;
            float4 v = *(const float4*)(x + ((size_t)(b * C_ + c0 + ci) * 128 + t) * 64 + v4 * 4);
            *(float4*)&Lt[ci][v4 * 4] = v;
            macc[i].x += v.x; macc[i].y += v.y; macc[i].z += v.z; macc[i].w += v.w;
        }
        __syncthreads();
        #pragma unroll
        for (int i = 0; i < 2; i++) {
            int p = tid + i * 256;
            int v = p & 63, qq = (p >> 6) & 3, cc2 = p >> 8;
            int cl0 = cc2 * 32 + qq * 8;
            uint4 u;
            u.x = pack2(Lt[cl0 + 0][v], Lt[cl0 + 1][v]);
            u.y = pack2(Lt[cl0 + 2][v], Lt[cl0 + 3][v]);
            u.z = pack2(Lt[cl0 + 4][v], Lt[cl0 + 5][v]);
            u.w = pack2(Lt[cl0 + 6][v], Lt[cl0 + 7][v]);
            int cc = cg * 2 + cc2;
            size_t dst = ((size_t)(b * 128 + t) * 8 + cc) * 2048 + qq * 512 + v * 8;
            *(uint4*)(img + dst) = u;
        }
        __syncthreads();
    }
    const float r = 1.0f / (float)T_;
    #pragma unroll
    for (int i = 0; i < 4; i++) {
        int e = tid + i * 256;
        int ci = e >> 4, v4 = e & 15;
        float* dst = tp + (size_t)(b * C_ + c0 + ci) * V_ + v4 * 4;
        atomicAdd(&dst[0], macc[i].x * r); atomicAdd(&dst[1], macc[i].y * r);
        atomicAdd(&dst[2], macc[i].z * r); atomicAdd(&dst[3], macc[i].w * r);
    }
}

/* x1/x2 partials over 64-c chunk, atomic into zeroed x1/x2 */
__global__ __launch_bounds__(256) void k_x1x2a(const float* __restrict__ tp,
                                               const float* __restrict__ w1, const float* __restrict__ b1,
                                               const float* __restrict__ w2, const float* __restrict__ b2,
                                               float* __restrict__ x1, float* __restrict__ x2) {
    int og = blockIdx.x, cc = blockIdx.y, b = blockIdx.z;
    int o  = og * 16 + (threadIdx.x >> 4);
    int v4 = threadIdx.x & 15;
    const float4* ptp = (const float4*)(tp + (size_t)b * C_ * V_) + v4;
    float4 s1 = {0.f,0.f,0.f,0.f}, s2 = {0.f,0.f,0.f,0.f};
    int c0 = cc * 64;
    for (int c = c0; c < c0 + 64; c++) {
        float4 tv = ptp[c * 16];
        float wa = w1[o * C_ + c];
        float wb = w2[o * C_ + c];
        s1.x += tv.x * wa; s1.y += tv.y * wa; s1.z += tv.z * wa; s1.w += tv.w * wa;
        s2.x += tv.x * wb; s2.y += tv.y * wb; s2.z += tv.z * wb; s2.w += tv.w * wb;
    }
    if (cc == 0) {
        float bv1 = b1[o], bv2 = b2[o];
        s1.x += bv1; s1.y += bv1; s1.z += bv1; s1.w += bv1;
        s2.x += bv2; s2.y += bv2; s2.z += bv2; s2.w += bv2;
    }
    float* p1 = x1 + (size_t)(b * O_ + o) * V_ + v4 * 4;
    float* p2 = x2 + (size_t)(b * O_ + o) * V_ + v4 * 4;
    atomicAdd(&p1[0], s1.x); atomicAdd(&p1[1], s1.y); atomicAdd(&p1[2], s1.z); atomicAdd(&p1[3], s1.w);
    atomicAdd(&p2[0], s2.x); atomicAdd(&p2[1], s2.y); atomicAdd(&p2[2], s2.z); atomicAdd(&p2[3], s2.w);
}

/* ada[b,k,v,w] = softmax_v( sum_c x1[b,k,c,v]*x2[b,k,c,w] ) one wave per (b,k,w) */
__global__ __launch_bounds__(64) void k_ada(const float* __restrict__ x1,
                                            const float* __restrict__ x2,
                                            float* __restrict__ ada) {
    int bid = blockIdx.x;
    int w = bid & 63;
    int k = (bid >> 6) & 7;
    int b = bid >> 9;
    int v = threadIdx.x;
    const float* p1 = x1 + ((size_t)b * O_ + k * 32) * V_;
    const float* p2 = x2 + ((size_t)b * O_ + k * 32) * V_;
    float s = 0.f;
    #pragma unroll
    for (int c = 0; c < 32; c++) s += p1[c * V_ + v] * p2[c * V_ + w];
    float m = s;
    #pragma unroll
    for (int off = 32; off >= 1; off >>= 1) m = fmaxf(m, __shfl_xor(m, off, 64));
    float e = __expf(s - m);
    float sum = e;
    #pragma unroll
    for (int off = 32; off >= 1; off >>= 1) sum += __shfl_xor(sum, off, 64);
    ada[((size_t)(b * K_ + k) * V_ + v) * V_ + w] = e / sum;
}

/* w[256][256] fp32 -> bf16 image: [cc 8][q 4][ol 256][cl 8] */
__global__ __launch_bounds__(256) void k_wconv(const float* __restrict__ w,
                                               ushort_t* __restrict__ img) {
    int flat = blockIdx.x * 256 + threadIdx.x;
    #pragma unroll
    for (int g2 = 0; g2 < 2; g2++) {
        int gi = flat * 2 + g2;
        int cc = gi >> 10;
        int q  = (gi >> 8) & 3;
        int ol = gi & 255;
        int c0 = cc * 32 + q * 8;
        const float* src = w + (size_t)ol * C_ + c0;
        float4 f0 = *(const float4*)src;
        float4 f1 = *(const float4*)(src + 4);
        uint4 u;
        u.x = pack2(f0.x, f0.y); u.y = pack2(f0.z, f0.w);
        u.z = pack2(f1.x, f1.y); u.w = pack2(f1.z, f1.w);
        *(uint4*)(img + (size_t)gi * 8) = u;
    }
}

/* out[b][o][n] = bf16( sum_c W[o][c] X[b][n][c] + bias[o] ); fused exact-fp32 BN stats
   into sliced accumulators psum/psumsq [NSL][256]. */
__global__ __launch_bounds__(256) void k_gemm(const ushort_t* __restrict__ ximg,
                                              const ushort_t* __restrict__ wimg,
                                              const float* __restrict__ bias,
                                              ushort_t* __restrict__ out,
                                              float* __restrict__ psum,
                                              float* __restrict__ psumsq) {
    __shared__ __align__(16) ushort_t sh[2048];
    int tid = threadIdx.x;
    int nblk = blockIdx.x, b = blockIdx.z;
    int wm = tid >> 6;
    int lane = tid & 63, ln = lane & 15, q = lane >> 4;
    f32x4 acc[4][4];
    #pragma unroll
    for (int mt = 0; mt < 4; mt++)
        #pragma unroll
        for (int nt = 0; nt < 4; nt++) acc[mt][nt] = (f32x4){0.f, 0.f, 0.f, 0.f};
    const ushort_t* xbase = ximg + ((size_t)(b * 128 + nblk) * 8) * 2048;
    for (int cc = 0; cc < 8; cc++) {
        gload_lds16(xbase + (size_t)cc * 2048 + wm * 512 + lane * 8, &sh[wm * 512]);
        __syncthreads();
        short8 a[4], bb[4];
        const ushort_t* wc = wimg + (size_t)cc * 8192 + q * 2048;
        #pragma unroll
        for (int mt = 0; mt < 4; mt++)
            a[mt] = *(const short8*)(wc + (wm * 64 + mt * 16 + ln) * 8);
        #pragma unroll
        for (int nt = 0; nt < 4; nt++)
            bb[nt] = *(const short8*)&sh[q * 512 + (nt * 16 + ln) * 8];
        #pragma unroll
        for (int mt = 0; mt < 4; mt++)
            #pragma unroll
            for (int nt = 0; nt < 4; nt++)
                acc[mt][nt] = __builtin_amdgcn_mfma_f32_16x16x32_bf16(a[mt], bb[nt], acc[mt][nt], 0, 0, 0);
        __syncthreads();
    }
    int n_base = nblk * 64;
    int slice = (nblk ^ (b << 3)) & (NSL - 1);
    #pragma unroll
    for (int mt = 0; mt < 4; mt++) {
        int o0 = wm * 64 + mt * 16 + q * 4;
        #pragma unroll
        for (int r = 0; r < 4; r++) {
            float bv = bias[o0 + r];
            float v0 = acc[mt][0][r] + bv, v1 = acc[mt][1][r] + bv;
            float v2 = acc[mt][2][r] + bv, v3 = acc[mt][3][r] + bv;
            ushort_t* orow = out + ((size_t)(b * O_ + o0 + r)) * TN + n_base + ln;
            orow[0] = f2bf(v0); orow[16] = f2bf(v1); orow[32] = f2bf(v2); orow[48] = f2bf(v3);
            float s  = v0 + v1 + v2 + v3;
            float sq = v0 * v0 + v1 * v1 + v2 * v2 + v3 * v3;
            #pragma unroll
            for (int off = 1; off <= 8; off <<= 1) {
                s  += __shfl_xor(s,  off, 64);
                sq += __shfl_xor(sq, off, 64);
            }
            if (ln == 0) {
                atomicAdd(&psum[slice * 256 + o0 + r],   s);
                atomicAdd(&psumsq[slice * 256 + o0 + r], sq);
            }
        }
    }
}

__global__ void k_finalize(const float* __restrict__ psum, const float* __restrict__ psumsq,
                           const float* __restrict__ gamma, const float* __restrict__ betap,
                           float* __restrict__ scale, float* __restrict__ shift) {
    int o = threadIdx.x;
    float s = 0.f, sq = 0.f;
    #pragma unroll
    for (int sl = 0; sl < NSL; sl++) {
        s  += psum[sl * 256 + o];
        sq += psumsq[sl * 256 + o];
    }
    float mean = s  * (1.0f / (float)NBT);
    float var  = sq * (1.0f / (float)NBT) - mean * mean;
    float sc = gamma[o] * rsqrtf(var + 1e-5f);
    scale[o] = sc;
    shift[o] = betap[o] - mean * sc;
}

/* MFMA einsum: per block (b,k,q,mh): 8 channels o1=k*32+q*8+cl, t-range mh*64..+63.
   h2img[(b*128+t)*8+k, q*512 + w*8 + cl] = sum_v relu(bn(z[b,o1,t,v])) * A[b,k,c,v,w]
   z is bf16. */
__global__ __launch_bounds__(256) void k_einsum_mfma(const ushort_t* __restrict__ z,
                                                     const float* __restrict__ x1,
                                                     const float* __restrict__ x2,
                                                     const float* __restrict__ ada,
                                                     const float* __restrict__ A_param,
                                                     const float* __restrict__ alphap,
                                                     const float* __restrict__ betap,
                                                     const float* __restrict__ scale,
                                                     const float* __restrict__ shift,
                                                     ushort_t* __restrict__ h2img) {
    __shared__ float Coms[4096];
    __shared__ float x1s[8][64], x2s[8][64];
    __shared__ __align__(16) ushort_t stg[8192];
    int tid = threadIdx.x;
    int bid = blockIdx.x;
    int mh = bid & 1;
    int q  = (bid >> 1) & 3;
    int k  = (bid >> 3) & 7;
    int b  = bid >> 6;
    int wm = tid >> 6;
    int lane = tid & 63, ln = lane & 15, qq = lane >> 4;
    float alpha = alphap[0], beta = betap[0];

    const float* Apk = A_param + (size_t)k * 4096;
    const float* adk = ada + (size_t)(b * K_ + k) * 4096;
    #pragma unroll
    for (int i = 0; i < 4; i++) {
        int e4 = tid + i * 256;
        float4 ap = *(const float4*)(Apk + (size_t)e4 * 4);
        float4 ad = *(const float4*)(adk + (size_t)e4 * 4);
        float4 cm = {ap.x + beta * ad.x, ap.y + beta * ad.y,
                     ap.z + beta * ad.z, ap.w + beta * ad.w};
        *(float4*)&Coms[e4 * 4] = cm;
    }
    #pragma unroll
    for (int i = 0; i < 2; i++) {
        int e = tid + i * 256;
        int cl = e >> 6, v = e & 63;
        int o1 = k * 32 + q * 8 + cl;
        x1s[cl][v] = x1[((size_t)b * O_ + o1) * V_ + v];
        x2s[cl][v] = x2[((size_t)b * O_ + o1) * V_ + v];
    }
    __syncthreads();

    short8 bfrag[2][2][4];
    #pragma unroll
    for (int half = 0; half < 2; half++) {
        int cl = wm + half * 4;
        #pragma unroll
        for (int kk = 0; kk < 2; kk++) {
            float x1v[8];
            #pragma unroll
            for (int j = 0; j < 8; j++) x1v[j] = x1s[cl][kk * 32 + qq * 8 + j];
            #pragma unroll
            for (int nt = 0; nt < 4; nt++) {
                int w = nt * 16 + ln;
                float x2v = x2s[cl][w];
                float av[8];
                #pragma unroll
                for (int j = 0; j < 8; j++) {
                    int v = kk * 32 + qq * 8 + j;
                    float d = x1v[j] - x2v;
                    float ax = fabsf(d);
                    float e2 = __expf(-2.f * ax);
                    float th = copysignf((1.f - e2) / (1.f + e2), d);
                    av[j] = Coms[v * 64 + w] + alpha * th;
                }
                uint4 bp;
                bp.x = pack2(av[0], av[1]); bp.y = pack2(av[2], av[3]);
                bp.z = pack2(av[4], av[5]); bp.w = pack2(av[6], av[7]);
                bfrag[half][kk][nt] = __builtin_bit_cast(short8, bp);
            }
        }
    }

    int o1a = k * 32 + q * 8 + wm;
    int o1b = o1a + 4;
    float scv[2] = {scale[o1a], scale[o1b]};
    float shv[2] = {shift[o1a], shift[o1b]};
    const ushort_t* zr[2] = {z + ((size_t)b * O_ + o1a) * TN, z + ((size_t)b * O_ + o1b) * TN};
    size_t obase = ((size_t)(b * 128) * 8 + k) * 2048 + q * 512;

    for (int mt = mh * 4; mt < mh * 4 + 4; mt++) {
        f32x4 acc[2][4];
        #pragma unroll
        for (int half = 0; half < 2; half++)
            #pragma unroll
            for (int nt = 0; nt < 4; nt++) acc[half][nt] = (f32x4){0.f, 0.f, 0.f, 0.f};
        #pragma unroll
        for (int half = 0; half < 2; half++) {
            float s = scv[half], h = shv[half];
            #pragma unroll
            for (int kk = 0; kk < 2; kk++) {
                const ushort_t* src = zr[half] + (mt * 16 + ln) * 64 + kk * 32 + qq * 8;
                uint4 zv = *(const uint4*)src;
                float f0 = bf2f_lo(zv.x), f1 = bf2f_hi(zv.x);
                float f2 = bf2f_lo(zv.y), f3 = bf2f_hi(zv.y);
                float f4 = bf2f_lo(zv.z), f5 = bf2f_hi(zv.z);
                float f6 = bf2f_lo(zv.w), f7 = bf2f_hi(zv.w);
                uint4 hp;
                hp.x = pack2(fmaxf(f0 * s + h, 0.f), fmaxf(f1 * s + h, 0.f));
                hp.y = pack2(fmaxf(f2 * s + h, 0.f), fmaxf(f3 * s + h, 0.f));
                hp.z = pack2(fmaxf(f4 * s + h, 0.f), fmaxf(f5 * s + h, 0.f));
                hp.w = pack2(fmaxf(f6 * s + h, 0.f), fmaxf(f7 * s + h, 0.f));
                short8 hf = __builtin_bit_cast(short8, hp);
                #pragma unroll
                for (int nt = 0; nt < 4; nt++)
                    acc[half][nt] = __builtin_amdgcn_mfma_f32_16x16x32_bf16(hf, bfrag[half][kk][nt], acc[half][nt], 0, 0, 0);
            }
        }
        #pragma unroll
        for (int half = 0; half < 2; half++) {
            int cl = wm + half * 4;
            #pragma unroll
            for (int nt = 0; nt < 4; nt++)
                #pragma unroll
                for (int r = 0; r < 4; r++)
                    stg[(qq * 4 + r) * 512 + (nt * 16 + ln) * 8 + cl] = f2bf(acc[half][nt][r]);
        }
        __syncthreads();
        #pragma unroll
        for (int ii = 0; ii < 4; ii++) {
            int u = tid + ii * 256;
            int tl = u >> 6, off = u & 63;
            ((uint4*)(h2img + obase + (size_t)(mt * 16 + tl) * 16384))[off] = ((const uint4*)stg)[u];
        }
        __syncthreads();
    }
}

/* out = relu(bn(u) + x); u is bf16 pre-BN, out fp32 */
__global__ __launch_bounds__(256) void k_final(const ushort_t* __restrict__ ub,
                                               const float* __restrict__ x,
                                               const float* __restrict__ scale,
                                               const float* __restrict__ shift,
                                               float* __restrict__ out) {
    size_t i4 = (size_t)blockIdx.x * 256 + threadIdx.x;
    int o = (int)((i4 >> 11) & 255);
    uint2 uv = ((const uint2*)ub)[i4];
    float4 xv = ((const float4*)x)[i4];
    float sc = scale[o], sh = shift[o];
    float4 r;
    r.x = fmaxf(bf2f_lo(uv.x) * sc + sh + xv.x, 0.f);
    r.y = fmaxf(bf2f_hi(uv.x) * sc + sh + xv.y, 0.f);
    r.z = fmaxf(bf2f_lo(uv.y) * sc + sh + xv.z, 0.f);
    r.w = fmaxf(bf2f_hi(uv.y) * sc + sh + xv.w, 0.f);
    ((float4*)out)[i4] = r;
}

extern "C" void kernel_launch(void* const* d_in, const int* in_sizes, int n_in,
                              void* d_out, int out_size, void* d_ws, size_t ws_size,
                              hipStream_t stream) {
    const float* x          = (const float*)d_in[0];
    const float* A_param    = (const float*)d_in[1];
    const float* alphap     = (const float*)d_in[2];
    const float* betap      = (const float*)d_in[3];
    const float* w1         = (const float*)d_in[4];
    const float* b1         = (const float*)d_in[5];
    const float* w2         = (const float*)d_in[6];
    const float* b2         = (const float*)d_in[7];
    const float* stem_w     = (const float*)d_in[8];
    const float* stem_b     = (const float*)d_in[9];
    const float* stem_gamma = (const float*)d_in[10];
    const float* stem_beta  = (const float*)d_in[11];
    const float* head_w     = (const float*)d_in[12];
    const float* head_b     = (const float*)d_in[13];
    const float* head_gamma = (const float*)d_in[14];
    const float* head_beta  = (const float*)d_in[15];

    float* W      = (float*)d_ws;
    float* tp     = W + OFF_TP;
    float* x1b    = W + OFF_X1;
    float* x2b    = W + OFF_X2;
    float* ssum   = W + OFF_STATS;               /* [NSL][256] */
    float* ssq    = W + OFF_STATS + NSL * 256;
    float* hsum   = W + OFF_STATS + NSL * 512;
    float* hsq    = W + OFF_STATS + NSL * 768;
    float* sscale = W + OFF_SSC;
    float* sshift = W + OFF_SSC + 256;
    float* hscale = W + OFF_HSC;
    float* hshift = W + OFF_HSC + 256;
    float* adab   = W + OFF_ADA;
    float* uout   = (float*)d_out;

    ushort_t* xTimg  = (ushort_t*)d_out;          /* dead before k_final writes d_out */
    ushort_t* wsimg  = (ushort_t*)(W + OFF_TP);   /* tp region, after x1x2 */
    ushort_t* whimg  = (ushort_t*)(W + OFF_TP + 32768);
    ushort_t* zb16   = (ushort_t*)(W + OFF_Z);    /* z bf16; u reuses it after einsum */
    ushort_t* ub16   = zb16;
    ushort_t* h2img  = (ushort_t*)(W + OFF_H2);

    /* zero tp, x1, x2, sliced stats (contiguous) */
    hipMemsetAsync(W, 0, (size_t)(OFF_STATS + NSL * 1024) * sizeof(float), stream);

    k_xpose2<<<dim3(8, 4, 16), 256, 0, stream>>>(x, xTimg, tp);
    k_x1x2a<<<dim3(16, 4, 16), 256, 0, stream>>>(tp, w1, b1, w2, b2, x1b, x2b);
    k_ada<<<8192, 64, 0, stream>>>(x1b, x2b, adab);
    k_wconv<<<16, 256, 0, stream>>>(stem_w, wsimg);
    k_wconv<<<16, 256, 0, stream>>>(head_w, whimg);

    k_gemm<<<dim3(128, 1, 16), 256, 0, stream>>>(xTimg, wsimg, stem_b, zb16, ssum, ssq);
    k_finalize<<<1, 256, 0, stream>>>(ssum, ssq, stem_gamma, stem_beta, sscale, sshift);

    k_einsum_mfma<<<1024, 256, 0, stream>>>(zb16, x1b, x2b, adab, A_param, alphap, betap,
                                            sscale, sshift, h2img);

    k_gemm<<<dim3(128, 1, 16), 256, 0, stream>>>(h2img, whimg, head_b, ub16, hsum, hsq);
    k_finalize<<<1, 256, 0, stream>>>(hsum, hsq, head_gamma, head_beta, hscale, hshift);
    k_final<<<32768, 256, 0, stream>>>(ub16, x, hscale, hshift, uout);
}